// Round 1
// baseline (254.922 us; speedup 1.0000x reference)
//
#include <hip/hip_runtime.h>

#define T_STEPS 512
#define LOG2E 1.4426950408889634f

// sigmoid(x) = 1 / (1 + exp(-x))   via hw exp2 + rcp
__device__ __forceinline__ float fsigmoid(float x) {
    float e = __builtin_amdgcn_exp2f(-LOG2E * x);
    return __builtin_amdgcn_rcpf(1.0f + e);
}
// tanh(x) = 1 - 2/(1 + exp(2x));  saturates correctly at +/-inf
__device__ __forceinline__ float ftanh(float x) {
    float e = __builtin_amdgcn_exp2f(2.0f * LOG2E * x);
    return 1.0f - 2.0f * __builtin_amdgcn_rcpf(1.0f + e);
}

// 8 lanes per batch element: lane j owns hidden unit j (its 4 gate rows).
// Work-optimal: 48 FMA + 5 activation evals per lane-step, no redundancy.
__global__ __launch_bounds__(256) void lstm_kernel(
    const float* __restrict__ x, const float* __restrict__ W_ih,
    const float* __restrict__ W_hh, const float* __restrict__ b_ih,
    const float* __restrict__ b_hh, const float* __restrict__ W_fc,
    const float* __restrict__ b_fc, float* __restrict__ out, int B)
{
    const int tid = blockIdx.x * blockDim.x + threadIdx.x;
    const int b = tid >> 3;               // batch element
    if (b >= B) return;
    const int j = threadIdx.x & 7;        // hidden unit
    const int lane = threadIdx.x & 63;
    const int pbase = (lane & 56) << 2;   // byte addr of lane group base for bpermute

    // Loop-invariant weights into registers: rows {j, 8+j, 16+j, 24+j} = i,f,g,o
    float wih[4][4], whh[4][8], bias[4];
    #pragma unroll
    for (int g = 0; g < 4; ++g) {
        const int r = g * 8 + j;
        #pragma unroll
        for (int k = 0; k < 4; ++k) wih[g][k] = W_ih[r * 4 + k];
        #pragma unroll
        for (int k = 0; k < 8; ++k) whh[g][k] = W_hh[r * 8 + k];
        bias[g] = b_ih[r] + b_hh[r];
    }

    const float4* xb = (const float4*)(x + (size_t)b * (T_STEPS * 4));
    float4 xt = xb[0];                    // prefetched x_t
    float c = 0.0f, h = 0.0f;

    for (int t = 0; t < T_STEPS; ++t) {
        // Prefetch next timestep's input (wraps to 0 on last iter; value unused)
        float4 xn = xb[(t + 1) & (T_STEPS - 1)];

        // All-gather h across the 8-lane group: 8 independent bpermutes
        const int hi = __float_as_int(h);
        float v[8];
        #pragma unroll
        for (int m = 0; m < 8; ++m)
            v[m] = __int_as_float(__builtin_amdgcn_ds_bpermute(pbase + 4 * m, hi));

        // 4 gate pre-activations: bias + x_t . W_ih_row + h . W_hh_row
        float ga[4];
        #pragma unroll
        for (int g = 0; g < 4; ++g) {
            float a = bias[g];
            a = fmaf(xt.x, wih[g][0], a);
            a = fmaf(xt.y, wih[g][1], a);
            a = fmaf(xt.z, wih[g][2], a);
            a = fmaf(xt.w, wih[g][3], a);
            #pragma unroll
            for (int m = 0; m < 8; ++m) a = fmaf(v[m], whh[g][m], a);
            ga[g] = a;
        }

        const float ig = fsigmoid(ga[0]) * ftanh(ga[2]);  // i * g
        const float f_ = fsigmoid(ga[1]);
        const float o_ = fsigmoid(ga[3]);
        c = fmaf(f_, c, ig);
        h = o_ * ftanh(c);
        xt = xn;
    }

    // out[b] = h . W_fc + b_fc   (reduce over the 8-lane group)
    float p = h * W_fc[j];
    p += __shfl_xor(p, 1);
    p += __shfl_xor(p, 2);
    p += __shfl_xor(p, 4);
    if (j == 0) out[b] = p + b_fc[0];
}

extern "C" void kernel_launch(void* const* d_in, const int* in_sizes, int n_in,
                              void* d_out, int out_size, void* d_ws, size_t ws_size,
                              hipStream_t stream) {
    const float* x    = (const float*)d_in[0];
    const float* W_ih = (const float*)d_in[1];
    const float* W_hh = (const float*)d_in[2];
    const float* b_ih = (const float*)d_in[3];
    const float* b_hh = (const float*)d_in[4];
    const float* W_fc = (const float*)d_in[5];
    const float* b_fc = (const float*)d_in[6];
    float* out = (float*)d_out;

    const int B = in_sizes[0] / (T_STEPS * 4);   // 8192
    const int threads = B * 8;
    const int block = 256;
    const int grid = (threads + block - 1) / block;
    lstm_kernel<<<grid, block, 0, stream>>>(x, W_ih, W_hh, b_ih, b_hh, W_fc, b_fc, out, B);
}

// Round 2
// 215.667 us; speedup vs baseline: 1.1820x; 1.1820x over previous
//
#include <hip/hip_runtime.h>

#define T_STEPS 512
#define UNROLL 8
#define LOG2E 1.4426950408889634f

// sigmoid(x) = 1 / (1 + exp(-x))   via hw exp2 + rcp
__device__ __forceinline__ float fsigmoid(float x) {
    float e = __builtin_amdgcn_exp2f(-LOG2E * x);
    return __builtin_amdgcn_rcpf(1.0f + e);
}
// tanh(x) = 1 - 2/(1 + exp(2x));  saturates correctly at +/-inf
__device__ __forceinline__ float ftanh(float x) {
    float e = __builtin_amdgcn_exp2f(2.0f * LOG2E * x);
    return 1.0f - 2.0f * __builtin_amdgcn_rcpf(1.0f + e);
}

// 8 lanes per batch element: lane j owns hidden unit j (its 4 gate rows).
// Work-optimal: 48 FMA + 5 activation evals per lane-step, no redundancy.
// x is prefetched 8 timesteps deep (register double-buffer) so the ~900-cycle
// HBM load latency is covered by ~2000 cycles of compute per 8-step block.
__global__ __launch_bounds__(256) void lstm_kernel(
    const float* __restrict__ x, const float* __restrict__ W_ih,
    const float* __restrict__ W_hh, const float* __restrict__ b_ih,
    const float* __restrict__ b_hh, const float* __restrict__ W_fc,
    const float* __restrict__ b_fc, float* __restrict__ out, int B)
{
    const int tid = blockIdx.x * blockDim.x + threadIdx.x;
    const int b = tid >> 3;               // batch element
    if (b >= B) return;
    const int j = threadIdx.x & 7;        // hidden unit
    const int lane = threadIdx.x & 63;
    const int pbase = (lane & 56) << 2;   // byte addr of lane group base for bpermute

    // Loop-invariant weights into registers: rows {j, 8+j, 16+j, 24+j} = i,f,g,o
    float wih[4][4], whh[4][8], bias[4];
    #pragma unroll
    for (int g = 0; g < 4; ++g) {
        const int r = g * 8 + j;
        #pragma unroll
        for (int k = 0; k < 4; ++k) wih[g][k] = W_ih[r * 4 + k];
        #pragma unroll
        for (int k = 0; k < 8; ++k) whh[g][k] = W_hh[r * 8 + k];
        bias[g] = b_ih[r] + b_hh[r];
    }

    const float4* xb = (const float4*)(x + (size_t)b * (T_STEPS * 4));

    float4 cur[UNROLL], nxt[UNROLL];
    #pragma unroll
    for (int k = 0; k < UNROLL; ++k) cur[k] = xb[k];

    float c = 0.0f, h = 0.0f;

    for (int base = 0; base < T_STEPS; base += UNROLL) {
        // Issue next block's loads up front; vmcnt drain happens only at the
        // copy at block end, by which time ~2000 cycles of compute have passed.
        const int nbase = (base + UNROLL < T_STEPS) ? base + UNROLL : 0;
        #pragma unroll
        for (int k = 0; k < UNROLL; ++k) nxt[k] = xb[nbase + k];

        #pragma unroll
        for (int k = 0; k < UNROLL; ++k) {
            const float4 xt = cur[k];

            // All-gather h across the 8-lane group: 8 independent bpermutes
            const int hi = __float_as_int(h);
            float v[8];
            #pragma unroll
            for (int m = 0; m < 8; ++m)
                v[m] = __int_as_float(__builtin_amdgcn_ds_bpermute(pbase + 4 * m, hi));

            // 4 gate pre-activations: bias + x_t . W_ih_row + h . W_hh_row
            float ga[4];
            #pragma unroll
            for (int g = 0; g < 4; ++g) {
                float a = bias[g];
                a = fmaf(xt.x, wih[g][0], a);
                a = fmaf(xt.y, wih[g][1], a);
                a = fmaf(xt.z, wih[g][2], a);
                a = fmaf(xt.w, wih[g][3], a);
                #pragma unroll
                for (int m = 0; m < 8; ++m) a = fmaf(v[m], whh[g][m], a);
                ga[g] = a;
            }

            const float ig = fsigmoid(ga[0]) * ftanh(ga[2]);  // i * g
            const float f_ = fsigmoid(ga[1]);
            const float o_ = fsigmoid(ga[3]);
            c = fmaf(f_, c, ig);
            h = o_ * ftanh(c);
        }

        #pragma unroll
        for (int k = 0; k < UNROLL; ++k) cur[k] = nxt[k];
    }

    // out[b] = h . W_fc + b_fc   (reduce over the 8-lane group)
    float p = h * W_fc[j];
    p += __shfl_xor(p, 1);
    p += __shfl_xor(p, 2);
    p += __shfl_xor(p, 4);
    if (j == 0) out[b] = p + b_fc[0];
}

extern "C" void kernel_launch(void* const* d_in, const int* in_sizes, int n_in,
                              void* d_out, int out_size, void* d_ws, size_t ws_size,
                              hipStream_t stream) {
    const float* x    = (const float*)d_in[0];
    const float* W_ih = (const float*)d_in[1];
    const float* W_hh = (const float*)d_in[2];
    const float* b_ih = (const float*)d_in[3];
    const float* b_hh = (const float*)d_in[4];
    const float* W_fc = (const float*)d_in[5];
    const float* b_fc = (const float*)d_in[6];
    float* out = (float*)d_out;

    const int B = in_sizes[0] / (T_STEPS * 4);   // 8192
    const int threads = B * 8;
    const int block = 256;
    const int grid = (threads + block - 1) / block;
    lstm_kernel<<<grid, block, 0, stream>>>(x, W_ih, W_hh, b_ih, b_hh, W_fc, b_fc, out, B);
}